// Round 10
// baseline (478.297 us; speedup 1.0000x reference)
//
#include <hip/hip_runtime.h>
#include <hip/hip_bf16.h>

#define BB 512
#define SS 1024
#define NI 20
#define HH 64
#define NG 256   // 4*H
#define MB4 4    // batch-dirs per block (1 cell per lane)
#define PAD 80   // h-row stride in f16
#define TSTR 257 // x-table row stride (floats)

typedef unsigned short u16;
typedef unsigned int u32;
typedef unsigned long long u64;
typedef _Float16 f16;
typedef f16 f16x8 __attribute__((ext_vector_type(8)));
typedef float f32x4 __attribute__((ext_vector_type(4)));

#define LOG2E 1.4426950408889634f

__device__ __forceinline__ float bf2f(u16 b) { return __uint_as_float(((u32)b) << 16); }
// mode==1: data is bf16; mode==0: data is fp32
__device__ __forceinline__ float ldw(const void* p, int idx, int mode) {
  return mode ? bf2f(((const u16*)p)[idx]) : ((const float*)p)[idx];
}
__device__ __forceinline__ float frcp(float x) { return __builtin_amdgcn_rcpf(x); }
__device__ __forceinline__ float fexp2(float x) { return __builtin_amdgcn_exp2f(x); }

__global__ void zero_kernel(float* p) {
  p[blockIdx.x * 256 + threadIdx.x] = 0.f;
}

// ---- BiLSTM + folded head contributions: 256 blocks x 256 thr, 1 wave/SIMD ----
// Block = (dir, 4 batches). Wave w owns units 16w..16w+15, 4 gate types in-lane;
// lane (l,q) = cell (batch q, unit 16w+l); A-rows dup h[l>>2] 4x. x-projection
// rides MFMA C-init from LDS table (prefetched 1 step ahead) -> 8 MFMA/step, now
// in 2 INDEPENDENT accumulators (K-chunk split) -> no serial MFMA C-dependency.
// Weights prescaled: i,f,o rows by -log2e, g rows by +2log2e (exp2-ready gates).
// Epilogue: everything after the LSTM is linear until softmax (fc1 has no act),
// so each block atomicAdds its fc1 contribution (W1-slice . h, and for bwd
// blocks also the conv path + b1) into global fc1acc; fin_kernel does fc2+softmax.
__global__ __launch_bounds__(256)
void lstm_kernel(const void* in1,
                 const void* Wih_f, const void* Whh_f, const void* b_f,
                 const void* Wih_b, const void* Whh_b, const void* b_b,
                 const void* conv1_w, const void* conv2_w, const void* conv2_b,
                 const void* fc1_w, const void* fc1_b,
                 float* fc1acc) {
  int bx = blockIdx.x;          // 0..255
  int dir = bx >> 7;
  int b0 = (bx & 127) * MB4;
  int t = threadIdx.x;
  int w = t >> 6, lane = t & 63, l = lane & 15, q = lane >> 4;
  int bsel = l >> 2;            // batch whose h this lane's A-row carries

  __shared__ __align__(16) float table[21 * TSTR];  // 21.6 KB; doubles as extract staging
  __shared__ __align__(16) f16 hbuf[2][MB4][PAD];
  __shared__ short tok_s[SS * MB4];                 // [pos][m], stores tok+1
  __shared__ u64 red[256];                          // reused as float scratch in epilogue
  __shared__ float w1s[64 * 65];                    // fc1_w dir-slice (padded)
  __shared__ float hs[MB4][64];                     // final h, f32
  __shared__ float c2r[MB4][100];                   // relu(c2) (bwd only)
  __shared__ float avg2[80];
  __shared__ float c1w2[400];
  __shared__ int mode_sh;

  // ---- mode probe: b_f read as bf16; fp32 shows wild exponents ----
  if (t == 0) mode_sh = 1;
  __syncthreads();
  {
    float v = bf2f(((const u16*)b_f)[t]);
    if (!(fabsf(v) < 1000.0f)) atomicAnd(&mode_sh, 0);
  }
  __syncthreads();
  int mode = mode_sh;
  const void* Wih = dir ? Wih_b : Wih_f;
  const void* Whh = dir ? Whh_b : Whh_f;
  const void* bv  = dir ? b_b   : b_f;

  // ---- token extraction for this block's 4 batches (staged through `table` memory) ----
  u64 cnt = 0;  // packed 4x16-bit valid counts
  for (int m = 0; m < MB4; ++m) {
    if (mode) {
      u32* st = (u32*)table;
      for (int k0 = 0; k0 < 4; ++k0) {
        const u32* src = (const u32*)in1 + ((size_t)(b0 + m) * SS + k0 * 256) * 10;
#pragma unroll
        for (int i = 0; i < 10; ++i) st[t + i * 256] = src[t + i * 256];  // coalesced
        __syncthreads();
        const u32* row = st + t * 10;
        int tok = -1;
#pragma unroll
        for (int ww = 0; ww < 10; ++ww) {
          u32 u = row[ww];
          if (u & 0xFFFFu) tok = 2 * ww;
          if (u >> 16)     tok = 2 * ww + 1;
        }
        tok_s[(k0 * 256 + t) * MB4 + m] = (short)(tok + 1);
        cnt += (u64)(tok >= 0) << (16 * m);
        __syncthreads();
      }
    } else {
      float4* st = (float4*)table;
      for (int k0 = 0; k0 < 4; ++k0) {
        const float4* src = (const float4*)((const float*)in1 + ((size_t)(b0 + m) * SS + k0 * 256) * 20);
#pragma unroll
        for (int i = 0; i < 5; ++i) st[t + i * 256] = src[t + i * 256];  // coalesced 16B/lane
        __syncthreads();
        const float* row = (const float*)table + t * 20;
        int tok = -1;
#pragma unroll
        for (int ww = 0; ww < 20; ++ww)
          if (row[ww] != 0.f) tok = ww;
        tok_s[(k0 * 256 + t) * MB4 + m] = (short)(tok + 1);
        cnt += (u64)(tok >= 0) << (16 * m);
        __syncthreads();
      }
    }
  }
  // lens: packed u64 tree reduction; all threads keep local copies
  red[t] = cnt;
  __syncthreads();
  for (int stp = 128; stp > 0; stp >>= 1) {
    if (t < stp) red[t] += red[t + stp];
    __syncthreads();
  }
  int len_m[MB4];
  {
    u64 r0 = red[0];
#pragma unroll
    for (int m = 0; m < MB4; ++m) len_m[m] = (int)((r0 >> (16 * m)) & 0xFFFFull);
  }
  __syncthreads();

  // ---- x-projection table: table[tok+1][g] = scl_g * (W_ih[g][tok] + b[g]); row 0 = bias ----
  for (int idx = t; idx < 21 * 256; idx += 256) {
    int r = idx >> 8, g = idx & 255;
    float scl = ((g >> 6) == 2) ? (2.f * LOG2E) : (-LOG2E);
    float v = ldw(bv, g, mode);
    if (r > 0) v += ldw(Wih, g * NI + (r - 1), mode);
    table[r * TSTR + g] = scl * v;
  }
  // ---- W_hh B-fragments: n=lane&15 -> gate col (unit 16w+l, type tt), k=q*8+j ----
  f16x8 Bf[4][2];
#pragma unroll
  for (int tt = 0; tt < 4; ++tt) {
    float scl = (tt == 2) ? (2.f * LOG2E) : (-LOG2E);
    int g = 64 * tt + 16 * w + l;
#pragma unroll
    for (int kc = 0; kc < 2; ++kc) {
      f16x8 v;
#pragma unroll
      for (int j = 0; j < 8; ++j)
        v[j] = (f16)(scl * ldw(Whh, g * HH + kc * 32 + q * 8 + j, mode));
      Bf[tt][kc] = v;
    }
  }
  for (int idx = t; idx < 2 * MB4 * PAD; idx += 256)
    ((f16*)hbuf)[idx] = (f16)0.f;
  __syncthreads();

  float c_st = 0.f, hlast = 0.f;
  int jj = 16 * w + l;
  int tbase = 16 * w + l;  // gate column offset within a table row
  const f32x4 z4 = {0.f, 0.f, 0.f, 0.f};

  // x-pipeline prologue: wx for s=0 (regs), tok for s=1 (reg)
  float wxc[4];
  {
    int pos0 = dir ? (SS - 1) : 0;
    int base = (int)tok_s[pos0 * MB4 + q] * TSTR + tbase;
    wxc[0] = table[base];       wxc[1] = table[base + 64];
    wxc[2] = table[base + 128]; wxc[3] = table[base + 192];
  }
  int tok1;
  {
    int pos1 = dir ? (SS - 2) : 1;
    tok1 = (int)tok_s[pos1 * MB4 + q];
  }

#pragma unroll 2
  for (int s = 0; s < SS; ++s) {
    int p = s & 1;
    // critical path: h fragments (A[m=l][k=q*8+j] = h[bsel][k], 4x dup rows)
    f16x8 a0 = *(const f16x8*)&hbuf[p][bsel][q * 8];
    f16x8 a1 = *(const f16x8*)&hbuf[p][bsel][32 + q * 8];
    // off-path: wx prefetch for s+1 (tok1 from pipeline), tok fetch for s+2
    float wxn[4];
    {
      int base = tok1 * TSTR + tbase;
      wxn[0] = table[base];       wxn[1] = table[base + 64];
      wxn[2] = table[base + 128]; wxn[3] = table[base + 192];
    }
    {
      int pos2 = (dir ? (SS - 3 - s) : (s + 2)) & (SS - 1);  // wrapped values unused
      tok1 = (int)tok_s[pos2 * MB4 + q];
    }

    // two INDEPENDENT accumulators per gate type (K-chunk split; no C-chaining)
    f32x4 accL[4], accH[4];
#pragma unroll
    for (int tt = 0; tt < 4; ++tt) {
      f32x4 ci = {wxc[tt], wxc[tt], wxc[tt], wxc[tt]};  // C-init = x-projection (+bias)
      accL[tt] = __builtin_amdgcn_mfma_f32_16x16x32_f16(a0, Bf[tt][0], ci, 0, 0, 0);
    }
#pragma unroll
    for (int tt = 0; tt < 4; ++tt)
      accH[tt] = __builtin_amdgcn_mfma_f32_16x16x32_f16(a1, Bf[tt][1], z4, 0, 0, 0);

    // activation (verified r6-r9): Ei=e^-i, Ef=e^-f, Eo=e^-o, G=e^2g
    {
      float Ei = fexp2(accL[0][0] + accH[0][0]);
      float Ef = fexp2(accL[1][0] + accH[1][0]);
      float G  = fexp2(accL[2][0] + accH[2][0]);
      float Eo = fexp2(accL[3][0] + accH[3][0]);
      float Ei1 = Ei + 1.f, Ef1 = Ef + 1.f, G1 = G + 1.f, Gm = G - 1.f;
      float t1 = Ei1 * G1;
      float num = fmaf(c_st, t1, Gm * Ef1);
      float cv = num * frcp(t1 * Ef1);
      c_st = cv;
      float C = fexp2((2.f * LOG2E) * cv);
      float hv = (C - 1.f) * frcp((Eo + 1.f) * (C + 1.f));
      hlast = hv;
      hbuf[p ^ 1][q][jj] = (f16)hv;
    }
    __syncthreads();
    wxc[0] = wxn[0]; wxc[1] = wxn[1]; wxc[2] = wxn[2]; wxc[3] = wxn[3];
  }

  // ================= epilogue: fold head's linear algebra =================
  hs[q][jj] = hlast;  // f32 h, shared across waves
  // stage fc1_w dir-slice coalesced: w1s[o][u] = fc1_w[o*228 + dir*64 + u]
  for (int i = t; i < 64 * 64; i += 256) {
    int o = i >> 6, u = i & 63;
    w1s[o * 65 + u] = ldw(fc1_w, o * 228 + dir * 64 + u, mode);
  }
  __syncthreads();

  float* fp = (float*)red;  // 512-float scratch
  // fc1 partial from this dir's h: thread (o=t&63, g=t>>6)
  for (int m = 0; m < MB4; ++m) {
    int o = t & 63, g = t >> 6;
    float v = 0.f;
#pragma unroll
    for (int u = g * 16; u < g * 16 + 16; ++u)
      v = fmaf(w1s[o * 65 + u], hs[m][u], v);
    fp[g * 64 + o] = v;
    __syncthreads();
    if (t < 64)
      atomicAdd(&fc1acc[(size_t)(b0 + m) * 64 + t],
                fp[t] + fp[64 + t] + fp[128 + t] + fp[192 + t]);
    __syncthreads();
  }

  if (dir == 1) {
    // conv path (verified r1-r9 logic), using local tok_s/len; contributes
    // W1[:,128:228].relu(c2) + b1 to fc1acc.
    for (int i = t; i < 400; i += 256) c1w2[i] = ldw(conv1_w, i, mode);
    __syncthreads();
    for (int m = 0; m < MB4; ++m) {
      int bw = len_m[m] >> 2;
      if (t < 160) {
        int half = t / 80, u = t - half * 80;
        int k = u / 20, cc = u % 20;
        int start = k * bw, mid = start + (bw >> 1), end = start + bw;
        int s0 = half ? mid : start, s1 = half ? end : mid;
        float sum = 0.f;
        for (int s = s0; s < s1; ++s) {
          // faithful torch reshape: flat f = s*20+cc of the [20,1024] map
          int f = s * 20 + cc;
          int tk = (int)tok_s[(f & 1023) * MB4 + m] - 1;
          if (tk >= 0) sum += c1w2[(f >> 10) * 20 + tk];
        }
        fp[half * 80 + u] = sum;
      }
      __syncthreads();
      if (t < 80) avg2[t] = (fp[t] + fp[80 + t]) / (float)bw;
      __syncthreads();
      if (t < 100) {
        float dot = ldw(conv2_b, t, mode);
#pragma unroll
        for (int qq = 0; qq < 80; ++qq)
          dot += avg2[qq] * ldw(conv2_w, t * 80 + qq, mode);
        c2r[m][t] = dot > 0.f ? dot : 0.f;  // relu
      }
      __syncthreads();
    }
    for (int m = 0; m < MB4; ++m) {
      int o = t & 63, g = t >> 6;
      float v = 0.f;
#pragma unroll
      for (int j = g * 25; j < g * 25 + 25; ++j)
        v = fmaf(ldw(fc1_w, o * 228 + 128 + j, mode), c2r[m][j], v);
      fp[g * 64 + o] = v;
      __syncthreads();
      if (t < 64)
        atomicAdd(&fc1acc[(size_t)(b0 + m) * 64 + t],
                  fp[t] + fp[64 + t] + fp[128 + t] + fp[192 + t] + ldw(fc1_b, t, mode));
      __syncthreads();
    }
  }
}

// ---- fc2 + softmax over accumulated fc1: 2 blocks x 256 threads, 1 batch/thread ----
__global__ void fin_kernel(const float* fc1acc, const void* fc2_w, const void* fc2_b,
                           const void* bvec, void* out) {
  int t = threadIdx.x;
  __shared__ int mode_sh;
  __shared__ float f2w[128];
  if (t == 0) mode_sh = 1;
  __syncthreads();
  {
    float v = bf2f(((const u16*)bvec)[t]);
    if (!(fabsf(v) < 1000.0f)) atomicAnd(&mode_sh, 0);
  }
  __syncthreads();
  int mode = mode_sh;
  if (t < 128) f2w[t] = ldw(fc2_w, t, mode);
  __syncthreads();

  int b = blockIdx.x * 256 + t;
  const float* f = fc1acc + (size_t)b * 64;
  float x0 = ldw(fc2_b, 0, mode), x1 = ldw(fc2_b, 1, mode);
#pragma unroll
  for (int m = 0; m < 64; ++m) {
    float fv = f[m];
    x0 = fmaf(fv, f2w[m], x0);
    x1 = fmaf(fv, f2w[64 + m], x1);
  }
  float mx = fmaxf(x0, x1);
  float e0 = fexp2(LOG2E * (x0 - mx)), e1 = fexp2(LOG2E * (x1 - mx));
  float inv = frcp(e0 + e1);
  if (mode) {
    ((__hip_bfloat16*)out)[b * 2 + 0] = __float2bfloat16(e0 * inv);
    ((__hip_bfloat16*)out)[b * 2 + 1] = __float2bfloat16(e1 * inv);
  } else {
    ((float*)out)[b * 2 + 0] = e0 * inv;
    ((float*)out)[b * 2 + 1] = e1 * inv;
  }
}

extern "C" void kernel_launch(void* const* d_in, const int* in_sizes, int n_in,
                              void* d_out, int out_size, void* d_ws, size_t ws_size,
                              hipStream_t stream) {
  (void)in_sizes; (void)n_in; (void)out_size; (void)ws_size;
  float* fc1acc = (float*)d_ws;  // 512*64 floats = 128 KB

  zero_kernel<<<128, 256, 0, stream>>>(fc1acc);
  lstm_kernel<<<256, 256, 0, stream>>>(d_in[0],
                                       d_in[1], d_in[2], d_in[3],
                                       d_in[4], d_in[5], d_in[6],
                                       d_in[7], d_in[8], d_in[9],
                                       d_in[10], d_in[11],
                                       fc1acc);
  fin_kernel<<<2, 256, 0, stream>>>(fc1acc, d_in[12], d_in[13], d_in[3], d_out);
}

// Round 11
// 442.951 us; speedup vs baseline: 1.0798x; 1.0798x over previous
//
#include <hip/hip_runtime.h>
#include <hip/hip_bf16.h>

#define BB 512
#define SS 1024
#define NI 20
#define HH 64
#define NG 256   // 4*H
#define MB4 4    // batch-dirs per block (1 cell per lane)
#define PAD 80   // h-row stride in f16
#define TSTR 257 // x-table row stride (floats)

typedef unsigned short u16;
typedef unsigned int u32;
typedef unsigned long long u64;
typedef _Float16 f16;
typedef f16 f16x8 __attribute__((ext_vector_type(8)));
typedef float f32x4 __attribute__((ext_vector_type(4)));

#define LOG2E 1.4426950408889634f

__device__ __forceinline__ float bf2f(u16 b) { return __uint_as_float(((u32)b) << 16); }
// mode==1: data is bf16; mode==0: data is fp32
__device__ __forceinline__ float ldw(const void* p, int idx, int mode) {
  return mode ? bf2f(((const u16*)p)[idx]) : ((const float*)p)[idx];
}
__device__ __forceinline__ float frcp(float x) { return __builtin_amdgcn_rcpf(x); }
__device__ __forceinline__ float fexp2(float x) { return __builtin_amdgcn_exp2f(x); }

// ---- BiLSTM + folded head contributions: 256 blocks x 256 thr, 1 wave/SIMD ----
// Block = (dir, 4 batches). Wave w owns units 16w..16w+15, 4 gate types in-lane;
// lane (l,q) = cell (batch q, unit 16w+l); A-rows dup h[l>>2] 4x. x-projection
// rides MFMA C-init from LDS table (prefetched 1 step ahead) -> 8 MFMA/step in
// ONE serial C-chain per gate type (r10 lesson: accumulator forwarding is free;
// splitting accumulators regressed 305->406 us via VALU-wait + register bloat).
// Weights prescaled: i,f,o rows by -log2e, g rows by +2log2e (exp2-ready gates).
// Epilogue: post-LSTM network is linear until softmax (fc1 has no activation),
// so each block atomicAdds its fc1 contribution (W1-slice . h; bwd blocks also
// conv path + b1) into global fc1acc; fin_kernel does fc2+softmax.
__global__ __launch_bounds__(256)
void lstm_kernel(const void* in1,
                 const void* Wih_f, const void* Whh_f, const void* b_f,
                 const void* Wih_b, const void* Whh_b, const void* b_b,
                 const void* conv1_w, const void* conv2_w, const void* conv2_b,
                 const void* fc1_w, const void* fc1_b,
                 float* fc1acc) {
  int bx = blockIdx.x;          // 0..255
  int dir = bx >> 7;
  int b0 = (bx & 127) * MB4;
  int t = threadIdx.x;
  int w = t >> 6, lane = t & 63, l = lane & 15, q = lane >> 4;
  int bsel = l >> 2;            // batch whose h this lane's A-row carries

  __shared__ __align__(16) float table[21 * TSTR];  // 21.6 KB; doubles as extract staging
  __shared__ __align__(16) f16 hbuf[2][MB4][PAD];
  __shared__ short tok_s[SS * MB4];                 // [pos][m], stores tok+1
  __shared__ u64 red[256];                          // reused as float scratch in epilogue
  __shared__ float w1s[64 * 65];                    // fc1_w dir-slice (padded)
  __shared__ float hs[MB4][64];                     // final h, f32
  __shared__ float c2r[MB4][100];                   // relu(c2) (bwd only)
  __shared__ float avg2[80];
  __shared__ float c1w2[400];
  __shared__ int mode_sh;

  // ---- mode probe: b_f read as bf16; fp32 shows wild exponents ----
  if (t == 0) mode_sh = 1;
  __syncthreads();
  {
    float v = bf2f(((const u16*)b_f)[t]);
    if (!(fabsf(v) < 1000.0f)) atomicAnd(&mode_sh, 0);
  }
  __syncthreads();
  int mode = mode_sh;
  const void* Wih = dir ? Wih_b : Wih_f;
  const void* Whh = dir ? Whh_b : Whh_f;
  const void* bv  = dir ? b_b   : b_f;

  // ---- token extraction for this block's 4 batches (staged through `table` memory) ----
  u64 cnt = 0;  // packed 4x16-bit valid counts
  for (int m = 0; m < MB4; ++m) {
    if (mode) {
      u32* st = (u32*)table;
      for (int k0 = 0; k0 < 4; ++k0) {
        const u32* src = (const u32*)in1 + ((size_t)(b0 + m) * SS + k0 * 256) * 10;
#pragma unroll
        for (int i = 0; i < 10; ++i) st[t + i * 256] = src[t + i * 256];  // coalesced
        __syncthreads();
        const u32* row = st + t * 10;
        int tok = -1;
#pragma unroll
        for (int ww = 0; ww < 10; ++ww) {
          u32 u = row[ww];
          if (u & 0xFFFFu) tok = 2 * ww;
          if (u >> 16)     tok = 2 * ww + 1;
        }
        tok_s[(k0 * 256 + t) * MB4 + m] = (short)(tok + 1);
        cnt += (u64)(tok >= 0) << (16 * m);
        __syncthreads();
      }
    } else {
      float4* st = (float4*)table;
      for (int k0 = 0; k0 < 4; ++k0) {
        const float4* src = (const float4*)((const float*)in1 + ((size_t)(b0 + m) * SS + k0 * 256) * 20);
#pragma unroll
        for (int i = 0; i < 5; ++i) st[t + i * 256] = src[t + i * 256];  // coalesced 16B/lane
        __syncthreads();
        const float* row = (const float*)table + t * 20;
        int tok = -1;
#pragma unroll
        for (int ww = 0; ww < 20; ++ww)
          if (row[ww] != 0.f) tok = ww;
        tok_s[(k0 * 256 + t) * MB4 + m] = (short)(tok + 1);
        cnt += (u64)(tok >= 0) << (16 * m);
        __syncthreads();
      }
    }
  }
  // lens: packed u64 tree reduction; all threads keep local copies
  red[t] = cnt;
  __syncthreads();
  for (int stp = 128; stp > 0; stp >>= 1) {
    if (t < stp) red[t] += red[t + stp];
    __syncthreads();
  }
  int len_m[MB4];
  {
    u64 r0 = red[0];
#pragma unroll
    for (int m = 0; m < MB4; ++m) len_m[m] = (int)((r0 >> (16 * m)) & 0xFFFFull);
  }
  __syncthreads();

  // ---- x-projection table: table[tok+1][g] = scl_g * (W_ih[g][tok] + b[g]); row 0 = bias ----
  for (int idx = t; idx < 21 * 256; idx += 256) {
    int r = idx >> 8, g = idx & 255;
    float scl = ((g >> 6) == 2) ? (2.f * LOG2E) : (-LOG2E);
    float v = ldw(bv, g, mode);
    if (r > 0) v += ldw(Wih, g * NI + (r - 1), mode);
    table[r * TSTR + g] = scl * v;
  }
  // ---- W_hh B-fragments: n=lane&15 -> gate col (unit 16w+l, type tt), k=q*8+j ----
  f16x8 Bf[4][2];
#pragma unroll
  for (int tt = 0; tt < 4; ++tt) {
    float scl = (tt == 2) ? (2.f * LOG2E) : (-LOG2E);
    int g = 64 * tt + 16 * w + l;
#pragma unroll
    for (int kc = 0; kc < 2; ++kc) {
      f16x8 v;
#pragma unroll
      for (int j = 0; j < 8; ++j)
        v[j] = (f16)(scl * ldw(Whh, g * HH + kc * 32 + q * 8 + j, mode));
      Bf[tt][kc] = v;
    }
  }
  for (int idx = t; idx < 2 * MB4 * PAD; idx += 256)
    ((f16*)hbuf)[idx] = (f16)0.f;
  __syncthreads();

  float c_st = 0.f, hlast = 0.f;
  int jj = 16 * w + l;
  int tbase = 16 * w + l;  // gate column offset within a table row

  // x-pipeline prologue: wx for s=0 (regs), tok for s=1 (reg)
  float wxc[4];
  {
    int pos0 = dir ? (SS - 1) : 0;
    int base = (int)tok_s[pos0 * MB4 + q] * TSTR + tbase;
    wxc[0] = table[base];       wxc[1] = table[base + 64];
    wxc[2] = table[base + 128]; wxc[3] = table[base + 192];
  }
  int tok1;
  {
    int pos1 = dir ? (SS - 2) : 1;
    tok1 = (int)tok_s[pos1 * MB4 + q];
  }

#pragma unroll 2
  for (int s = 0; s < SS; ++s) {
    int p = s & 1;
    // critical path: h fragments (A[m=l][k=q*8+j] = h[bsel][k], 4x dup rows)
    f16x8 a0 = *(const f16x8*)&hbuf[p][bsel][q * 8];
    f16x8 a1 = *(const f16x8*)&hbuf[p][bsel][32 + q * 8];
    // off-path: wx prefetch for s+1 (tok1 from pipeline), tok fetch for s+2
    float wxn[4];
    {
      int base = tok1 * TSTR + tbase;
      wxn[0] = table[base];       wxn[1] = table[base + 64];
      wxn[2] = table[base + 128]; wxn[3] = table[base + 192];
    }
    {
      int pos2 = (dir ? (SS - 3 - s) : (s + 2)) & (SS - 1);  // wrapped values unused
      tok1 = (int)tok_s[pos2 * MB4 + q];
    }

    // r9-verified serial C-chain: C-init = x-projection, 2-deep MFMA per gate type
    f32x4 acc[4];
#pragma unroll
    for (int tt = 0; tt < 4; ++tt) {
      f32x4 ci = {wxc[tt], wxc[tt], wxc[tt], wxc[tt]};
      acc[tt] = __builtin_amdgcn_mfma_f32_16x16x32_f16(a0, Bf[tt][0], ci, 0, 0, 0);
    }
#pragma unroll
    for (int tt = 0; tt < 4; ++tt)
      acc[tt] = __builtin_amdgcn_mfma_f32_16x16x32_f16(a1, Bf[tt][1], acc[tt], 0, 0, 0);

    // activation (verified r6-r9): Ei=e^-i, Ef=e^-f, Eo=e^-o, G=e^2g
    {
      float Ei = fexp2(acc[0][0]);
      float Ef = fexp2(acc[1][0]);
      float G  = fexp2(acc[2][0]);
      float Eo = fexp2(acc[3][0]);
      float Ei1 = Ei + 1.f, Ef1 = Ef + 1.f, G1 = G + 1.f, Gm = G - 1.f;
      float t1 = Ei1 * G1;
      float num = fmaf(c_st, t1, Gm * Ef1);
      float cv = num * frcp(t1 * Ef1);
      c_st = cv;
      float C = fexp2((2.f * LOG2E) * cv);
      float hv = (C - 1.f) * frcp((Eo + 1.f) * (C + 1.f));
      hlast = hv;
      hbuf[p ^ 1][q][jj] = (f16)hv;
    }
    __syncthreads();
    wxc[0] = wxn[0]; wxc[1] = wxn[1]; wxc[2] = wxn[2]; wxc[3] = wxn[3];
  }

  // ================= epilogue: fold head's linear algebra =================
  hs[q][jj] = hlast;  // f32 h, shared across waves
  // stage fc1_w dir-slice coalesced: w1s[o][u] = fc1_w[o*228 + dir*64 + u]
  for (int i = t; i < 64 * 64; i += 256) {
    int o = i >> 6, u = i & 63;
    w1s[o * 65 + u] = ldw(fc1_w, o * 228 + dir * 64 + u, mode);
  }
  __syncthreads();

  float* fp = (float*)red;  // 512-float scratch
  // fc1 partial from this dir's h: thread (o=t&63, g=t>>6)
  for (int m = 0; m < MB4; ++m) {
    int o = t & 63, g = t >> 6;
    float v = 0.f;
#pragma unroll
    for (int u = g * 16; u < g * 16 + 16; ++u)
      v = fmaf(w1s[o * 65 + u], hs[m][u], v);
    fp[g * 64 + o] = v;
    __syncthreads();
    if (t < 64)
      atomicAdd(&fc1acc[(size_t)(b0 + m) * 64 + t],
                fp[t] + fp[64 + t] + fp[128 + t] + fp[192 + t]);
    __syncthreads();
  }

  if (dir == 1) {
    // conv path (verified r1-r10 logic), using local tok_s/len; contributes
    // W1[:,128:228].relu(c2) + b1 to fc1acc.
    for (int i = t; i < 400; i += 256) c1w2[i] = ldw(conv1_w, i, mode);
    __syncthreads();
    for (int m = 0; m < MB4; ++m) {
      int bw = len_m[m] >> 2;
      if (t < 160) {
        int half = t / 80, u = t - half * 80;
        int k = u / 20, cc = u % 20;
        int start = k * bw, mid = start + (bw >> 1), end = start + bw;
        int s0 = half ? mid : start, s1 = half ? end : mid;
        float sum = 0.f;
        for (int s = s0; s < s1; ++s) {
          // faithful torch reshape: flat f = s*20+cc of the [20,1024] map
          int f = s * 20 + cc;
          int tk = (int)tok_s[(f & 1023) * MB4 + m] - 1;
          if (tk >= 0) sum += c1w2[(f >> 10) * 20 + tk];
        }
        fp[half * 80 + u] = sum;
      }
      __syncthreads();
      if (t < 80) avg2[t] = (fp[t] + fp[80 + t]) / (float)bw;
      __syncthreads();
      if (t < 100) {
        float dot = ldw(conv2_b, t, mode);
#pragma unroll
        for (int qq = 0; qq < 80; ++qq)
          dot += avg2[qq] * ldw(conv2_w, t * 80 + qq, mode);
        c2r[m][t] = dot > 0.f ? dot : 0.f;  // relu
      }
      __syncthreads();
    }
    for (int m = 0; m < MB4; ++m) {
      int o = t & 63, g = t >> 6;
      float v = 0.f;
#pragma unroll
      for (int j = g * 25; j < g * 25 + 25; ++j)
        v = fmaf(ldw(fc1_w, o * 228 + 128 + j, mode), c2r[m][j], v);
      fp[g * 64 + o] = v;
      __syncthreads();
      if (t < 64)
        atomicAdd(&fc1acc[(size_t)(b0 + m) * 64 + t],
                  fp[t] + fp[64 + t] + fp[128 + t] + fp[192 + t] + ldw(fc1_b, t, mode));
      __syncthreads();
    }
  }
}

// ---- fc2 + softmax over accumulated fc1: 2 blocks x 256 threads, 1 batch/thread ----
__global__ void fin_kernel(const float* fc1acc, const void* fc2_w, const void* fc2_b,
                           const void* bvec, void* out) {
  int t = threadIdx.x;
  __shared__ int mode_sh;
  __shared__ float f2w[128];
  if (t == 0) mode_sh = 1;
  __syncthreads();
  {
    float v = bf2f(((const u16*)bvec)[t]);
    if (!(fabsf(v) < 1000.0f)) atomicAnd(&mode_sh, 0);
  }
  __syncthreads();
  int mode = mode_sh;
  if (t < 128) f2w[t] = ldw(fc2_w, t, mode);
  __syncthreads();

  int b = blockIdx.x * 256 + t;
  const float* f = fc1acc + (size_t)b * 64;
  float x0 = ldw(fc2_b, 0, mode), x1 = ldw(fc2_b, 1, mode);
#pragma unroll
  for (int m = 0; m < 64; ++m) {
    float fv = f[m];
    x0 = fmaf(fv, f2w[m], x0);
    x1 = fmaf(fv, f2w[64 + m], x1);
  }
  float mx = fmaxf(x0, x1);
  float e0 = fexp2(LOG2E * (x0 - mx)), e1 = fexp2(LOG2E * (x1 - mx));
  float inv = frcp(e0 + e1);
  if (mode) {
    ((__hip_bfloat16*)out)[b * 2 + 0] = __float2bfloat16(e0 * inv);
    ((__hip_bfloat16*)out)[b * 2 + 1] = __float2bfloat16(e1 * inv);
  } else {
    ((float*)out)[b * 2 + 0] = e0 * inv;
    ((float*)out)[b * 2 + 1] = e1 * inv;
  }
}

extern "C" void kernel_launch(void* const* d_in, const int* in_sizes, int n_in,
                              void* d_out, int out_size, void* d_ws, size_t ws_size,
                              hipStream_t stream) {
  (void)in_sizes; (void)n_in; (void)out_size; (void)ws_size;
  float* fc1acc = (float*)d_ws;  // 512*64 floats = 128 KB

  hipMemsetAsync(fc1acc, 0, (size_t)BB * 64 * sizeof(float), stream);
  lstm_kernel<<<256, 256, 0, stream>>>(d_in[0],
                                       d_in[1], d_in[2], d_in[3],
                                       d_in[4], d_in[5], d_in[6],
                                       d_in[7], d_in[8], d_in[9],
                                       d_in[10], d_in[11],
                                       fc1acc);
  fin_kernel<<<2, 256, 0, stream>>>(fc1acc, d_in[12], d_in[13], d_in[3], d_out);
}